// Round 4
// baseline (424.302 us; speedup 1.0000x reference)
//
#include <hip/hip_runtime.h>
#include <stdint.h>

#define B   256
#define IU  8      // in_units (i)
#define JC  1152   // in_channels (j)
#define NN  10     // num_units (n)
#define UU  16     // unit_size (u)
#define NU  160    // NN*UU
#define JN  11520  // JC*NN

// ---------------- softmax over j axis: c[j,n] = softmax_j(b[j,n]) --------
__global__ void k_softmax(const float* __restrict__ blog, float* __restrict__ c) {
    int n = blockIdx.x;           // 0..9
    int tid = threadIdx.x;        // 256
    __shared__ float red[256];
    float m = -1e30f;
    for (int j = tid; j < JC; j += 256) m = fmaxf(m, blog[j*NN + n]);
    red[tid] = m; __syncthreads();
    for (int s = 128; s > 0; s >>= 1) {
        if (tid < s) red[tid] = fmaxf(red[tid], red[tid+s]);
        __syncthreads();
    }
    m = red[0]; __syncthreads();
    float sum = 0.f;
    for (int j = tid; j < JC; j += 256) sum += __expf(blog[j*NN + n] - m);
    red[tid] = sum; __syncthreads();
    for (int s = 128; s > 0; s >>= 1) {
        if (tid < s) red[tid] += red[tid+s];
        __syncthreads();
    }
    float inv = 1.f / red[0];
    for (int j = tid; j < JC; j += 256)
        c[j*NN + n] = __expf(blog[j*NN + n] - m) * inv;
}

// ---------------- heavy pass 1: sbuf[b][n*16+u] += c*u_hat (atomic) -------
// grid (18 j-tiles of 64, 32 b-tiles of 8), block 320.
// thread: js = tid&15 (j-split within wave), g = tid>>4: n = g>>1, uh = g&1.
__global__ void __launch_bounds__(320, 2)
k_uhat_s(const float* __restrict__ xg, const float* __restrict__ wg,
         const float* __restrict__ c, float* __restrict__ sbuf) {
    const int jt = blockIdx.x, bt = blockIdx.y;
    const int j0 = jt * 64, b0 = bt * 8;
    const int tid = threadIdx.x;
    const int js = tid & 15;
    const int g  = tid >> 4;       // 0..19
    const int n  = g >> 1;
    const int uh = g & 1;

    __shared__ float xs[64 * 68];  // xs[jl*68 + b*8 + i]
    __shared__ float cs[640];      // cs[jl*10 + n]

    for (int idx = tid; idx < 4096; idx += 320) {
        int jl = idx & 63;
        int r  = idx >> 6;
        int i  = r & 7;
        int b  = r >> 3;
        xs[jl*68 + b*8 + i] = xg[(size_t)(b0 + b) * (IU*JC) + i * JC + j0 + jl];
    }
    for (int idx = tid; idx < 640; idx += 320)
        cs[idx] = c[j0*NN + idx];
    __syncthreads();

    float acc[64];
    #pragma unroll
    for (int k = 0; k < 64; ++k) acc[k] = 0.f;

    #pragma unroll
    for (int jj = 0; jj < 4; ++jj) {
        const int jl = js*4 + jj;
        const int j  = j0 + jl;
        const float cc = cs[jl*NN + n];
        const float4* wp = reinterpret_cast<const float4*>(
            wg + (size_t)j * (NN*UU*IU) + n * (UU*IU) + uh * 64);
        float wf[64];
        #pragma unroll
        for (int r = 0; r < 16; ++r) {
            float4 wv = wp[r];
            wf[r*4+0] = wv.x * cc; wf[r*4+1] = wv.y * cc;
            wf[r*4+2] = wv.z * cc; wf[r*4+3] = wv.w * cc;
        }
        #pragma unroll
        for (int bb = 0; bb < 8; ++bb) {
            const float4* xp = reinterpret_cast<const float4*>(&xs[jl*68 + bb*8]);
            float4 x0 = xp[0], x1 = xp[1];
            #pragma unroll
            for (int r = 0; r < 8; ++r) {
                float a = acc[bb*8 + r];
                const float* w8 = &wf[r*8];
                a = fmaf(w8[0], x0.x, a); a = fmaf(w8[1], x0.y, a);
                a = fmaf(w8[2], x0.z, a); a = fmaf(w8[3], x0.w, a);
                a = fmaf(w8[4], x1.x, a); a = fmaf(w8[5], x1.y, a);
                a = fmaf(w8[6], x1.z, a); a = fmaf(w8[7], x1.w, a);
                acc[bb*8 + r] = a;
            }
        }
    }

    // butterfly over the 16 j-split lanes: every lane ends with full sums
    #pragma unroll
    for (int k = 0; k < 64; ++k) {
        float a = acc[k];
        a += __shfl_xor(a, 8);
        a += __shfl_xor(a, 4);
        a += __shfl_xor(a, 2);
        a += __shfl_xor(a, 1);
        acc[k] = a;
    }
    // each lane commits 4 of the 64 values (spread atomics across lanes)
    #pragma unroll
    for (int q = 0; q < 4; ++q) {
        int k  = js*4 + q;
        int bb = k >> 3;
        int r  = k & 7;
        atomicAdd(&sbuf[(size_t)(b0 + bb) * NU + n*16 + uh*8 + r], acc[k]);
    }
}

// ---------------- squash: vdst[b][t] = squash(sbuf)[b][t] ----------------
__global__ void k_reduce_s(const float* __restrict__ sbuf, float* __restrict__ vdst) {
    int b = blockIdx.x, t = threadIdx.x;   // 160 threads: t = n*16+u
    float s = sbuf[(size_t)b * NU + t];
    __shared__ float sv[NU];
    __shared__ float fb[UU];
    sv[t] = s; __syncthreads();
    if (t < UU) {
        float m = 0.f;
        #pragma unroll
        for (int n = 0; n < NN; ++n) { float z = sv[n*16 + t]; m = fmaf(z, z, m); }
        fb[t] = sqrtf(m) / (1.f + m);   // == (m/(1+m)) / sqrt(m)
    }
    __syncthreads();
    vdst[(size_t)b * NU + t] = s * fb[t & 15];
}

// ---------------- heavy pass 2: db[j*10+n] += <u_hat, v> (atomic) --------
// grid (36 j-tiles of 32, 16 b-tiles of 16), block 320: jl = tid&31, n = tid>>5.
__global__ void __launch_bounds__(320, 2)
k_uhat_db(const float* __restrict__ xg, const float* __restrict__ wg,
          const float* __restrict__ v, float* __restrict__ db) {
    const int jt = blockIdx.x, bt = blockIdx.y;
    const int j0 = jt * 32, b0 = bt * 16;
    const int tid = threadIdx.x;
    const int jl = tid & 31;
    const int n  = tid >> 5;     // 0..9

    __shared__ float xs2[4096];  // [((i>>2)*16+b)*32 + jl]*4 + (i&3)
    __shared__ float vs2[16 * NU];

    for (int idx = tid; idx < 4096; idx += 320) {
        int jj = idx & 31;
        int r  = idx >> 5;
        int i  = r & 7;
        int b  = r >> 3;
        xs2[(((i >> 2)*16 + b)*32 + jj)*4 + (i & 3)] =
            xg[(size_t)(b0 + b) * (IU*JC) + i * JC + j0 + jj];
    }
    for (int idx = tid; idx < 16*NU; idx += 320)
        vs2[idx] = v[(size_t)b0 * NU + idx];
    __syncthreads();

    const int j = j0 + jl;
    const float4* wp = reinterpret_cast<const float4*>(
        wg + (size_t)j * (NN*UU*IU) + n * (UU*IU));
    float wf[128];
    #pragma unroll
    for (int r = 0; r < 32; ++r) {
        float4 wv = wp[r];
        wf[r*4+0] = wv.x; wf[r*4+1] = wv.y;
        wf[r*4+2] = wv.z; wf[r*4+3] = wv.w;
    }

    float acc = 0.f;
    #pragma unroll 4
    for (int b = 0; b < 16; ++b) {
        const float4* xp0 = reinterpret_cast<const float4*>(&xs2[((b)*32 + jl)*4]);
        const float4* xp1 = reinterpret_cast<const float4*>(&xs2[((16 + b)*32 + jl)*4]);
        float4 xa = xp0[0], xb = xp1[0];
        const float4* vp = reinterpret_cast<const float4*>(&vs2[b*NU + n*16]);
        float4 v0 = vp[0], v1 = vp[1], v2 = vp[2], v3 = vp[3];
        float vr[16] = {v0.x,v0.y,v0.z,v0.w, v1.x,v1.y,v1.z,v1.w,
                        v2.x,v2.y,v2.z,v2.w, v3.x,v3.y,v3.z,v3.w};
        #pragma unroll
        for (int u = 0; u < 16; ++u) {
            const float* w8 = &wf[u*8];
            float t;
            t = w8[0] * xa.x;
            t = fmaf(w8[1], xa.y, t); t = fmaf(w8[2], xa.z, t);
            t = fmaf(w8[3], xa.w, t); t = fmaf(w8[4], xb.x, t);
            t = fmaf(w8[5], xb.y, t); t = fmaf(w8[6], xb.z, t);
            t = fmaf(w8[7], xb.w, t);
            acc = fmaf(t, vr[u], acc);
        }
    }
    atomicAdd(&db[(size_t)j * NN + n], acc);
}

// ---------------- b += db/B ----------------------------------------------
__global__ void k_update_b(const float* __restrict__ db, float* __restrict__ blog) {
    int k = blockIdx.x * 256 + threadIdx.x;
    if (k >= JN) return;
    blog[k] += db[k] * (1.f / (float)B);
}

extern "C" void kernel_launch(void* const* d_in, const int* in_sizes, int n_in,
                              void* d_out, int out_size, void* d_ws, size_t ws_size,
                              hipStream_t stream) {
    const float* x = (const float*)d_in[0];
    const float* w = (const float*)d_in[1];
    float* out = (float*)d_out;    // reference output dtype is float32

    float* ws   = (float*)d_ws;
    float* blog = ws;                 // 11520 floats
    float* c    = blog + JN;          // 11520
    float* sbuf = c + JN;             // 40960
    float* v    = sbuf + (size_t)B*NU;// 40960
    float* db   = v + (size_t)B*NU;   // 11520
    // total: 116480 floats = 465,920 bytes

    hipMemsetAsync(blog, 0, JN * sizeof(float), stream);

    for (int t = 0; t < 3; ++t) {
        k_softmax<<<NN, 256, 0, stream>>>(blog, c);
        hipMemsetAsync(sbuf, 0, (size_t)B * NU * sizeof(float), stream);
        k_uhat_s<<<dim3(18, 32), 320, 0, stream>>>(x, w, c, sbuf);
        // final iteration writes v directly to d_out (fp32)
        k_reduce_s<<<B, NU, 0, stream>>>(sbuf, (t == 2) ? out : v);
        if (t < 2) {
            hipMemsetAsync(db, 0, JN * sizeof(float), stream);
            k_uhat_db<<<dim3(36, 16), 320, 0, stream>>>(x, w, v, db);
            k_update_b<<<45, 256, 0, stream>>>(db, blog);
        }
    }
}

// Round 5
// 316.662 us; speedup vs baseline: 1.3399x; 1.3399x over previous
//
#include <hip/hip_runtime.h>
#include <stdint.h>

#define B   256
#define IU  8      // in_units (i)
#define JC  1152   // in_channels (j)
#define NN  10     // num_units (n)
#define UU  16     // unit_size (u)
#define NU  160    // NN*UU
#define JN  11520  // JC*NN
#define WROW 1280  // NN*UU*IU, floats per j in W

// ---------------- softmax over j axis: c[j,n] = softmax_j(b[j,n]) --------
__global__ void k_softmax(const float* __restrict__ blog, float* __restrict__ c) {
    int n = blockIdx.x;           // 0..9
    int tid = threadIdx.x;        // 256
    __shared__ float red[256];
    float m = -1e30f;
    for (int j = tid; j < JC; j += 256) m = fmaxf(m, blog[j*NN + n]);
    red[tid] = m; __syncthreads();
    for (int s = 128; s > 0; s >>= 1) {
        if (tid < s) red[tid] = fmaxf(red[tid], red[tid+s]);
        __syncthreads();
    }
    m = red[0]; __syncthreads();
    float sum = 0.f;
    for (int j = tid; j < JC; j += 256) sum += __expf(blog[j*NN + n] - m);
    red[tid] = sum; __syncthreads();
    for (int s = 128; s > 0; s >>= 1) {
        if (tid < s) red[tid] += red[tid+s];
        __syncthreads();
    }
    float inv = 1.f / red[0];
    for (int j = tid; j < JC; j += 256)
        c[j*NN + n] = __expf(blog[j*NN + n] - m) * inv;
}

// ---------------- heavy pass 1: sbuf[b][n*16+u] += c*u_hat (atomic) -------
// grid (18 j-tiles of 64, 32 b-tiles of 8), block 320.
// js = tid&7 (j-split, lane bits 0..2), g = tid>>3 (0..39): n = g>>2, uq = g&3.
// Per thread: 8 j's; regs: acc[8bb][4u]=32, wf[4u][8i]=32 -> no spills.
__global__ void __launch_bounds__(320, 2)
k_uhat_s(const float* __restrict__ xg, const float* __restrict__ wg,
         const float* __restrict__ c, float* __restrict__ sbuf) {
    const int jt = blockIdx.x, bt = blockIdx.y;
    const int j0 = jt * 64, b0 = bt * 8;
    const int tid = threadIdx.x;
    const int js = tid & 7;
    const int g  = tid >> 3;       // 0..39
    const int n  = g >> 2;
    const int uq = g & 3;

    __shared__ float xs[64 * 68];  // xs[jl*68 + b*8 + i]
    __shared__ float cs[640];      // cs[jl*10 + n]

    for (int idx = tid; idx < 4096; idx += 320) {
        int jl = idx & 63;
        int r  = idx >> 6;
        int i  = r & 7;
        int b  = r >> 3;
        xs[jl*68 + b*8 + i] = xg[(size_t)(b0 + b) * (IU*JC) + i * JC + j0 + jl];
    }
    for (int idx = tid; idx < 640; idx += 320)
        cs[idx] = c[j0*NN + idx];
    __syncthreads();

    float acc[32];                 // acc[bb*4 + u]
    #pragma unroll
    for (int k = 0; k < 32; ++k) acc[k] = 0.f;

    #pragma unroll
    for (int jj = 0; jj < 8; ++jj) {
        const int jl = jj*8 + js;
        const int j  = j0 + jl;
        const float cc = cs[jl*NN + n];
        const float4* wp = reinterpret_cast<const float4*>(
            wg + (size_t)j * WROW + n * (UU*IU) + uq * 32);
        float wf[32];              // wf[u*8 + i], u = 0..3 (within quarter)
        #pragma unroll
        for (int r = 0; r < 8; ++r) {
            float4 wv = wp[r];
            wf[r*4+0] = wv.x * cc; wf[r*4+1] = wv.y * cc;
            wf[r*4+2] = wv.z * cc; wf[r*4+3] = wv.w * cc;
        }
        #pragma unroll
        for (int bb = 0; bb < 8; ++bb) {
            const float4* xp = reinterpret_cast<const float4*>(&xs[jl*68 + bb*8]);
            float4 x0 = xp[0], x1 = xp[1];
            #pragma unroll
            for (int u = 0; u < 4; ++u) {
                const float* w8 = &wf[u*8];
                float a = acc[bb*4 + u];
                a = fmaf(w8[0], x0.x, a); a = fmaf(w8[1], x0.y, a);
                a = fmaf(w8[2], x0.z, a); a = fmaf(w8[3], x0.w, a);
                a = fmaf(w8[4], x1.x, a); a = fmaf(w8[5], x1.y, a);
                a = fmaf(w8[6], x1.z, a); a = fmaf(w8[7], x1.w, a);
                acc[bb*4 + u] = a;
            }
        }
    }

    // butterfly over the 8 j-split lanes (lane bits 0..2)
    #pragma unroll
    for (int k = 0; k < 32; ++k) {
        float a = acc[k];
        a += __shfl_xor(a, 4);
        a += __shfl_xor(a, 2);
        a += __shfl_xor(a, 1);
        acc[k] = a;
    }
    // lane js commits batch bb == js (4 u-values)
    #pragma unroll
    for (int u = 0; u < 4; ++u)
        atomicAdd(&sbuf[(size_t)(b0 + js) * NU + n*16 + uq*4 + u], acc[js*4 + u]);
}

// ---------------- squash: vdst[b][t] = squash(sbuf)[b][t] ----------------
__global__ void k_reduce_s(const float* __restrict__ sbuf, float* __restrict__ vdst) {
    int b = blockIdx.x, t = threadIdx.x;   // 160 threads: t = n*16+u
    float s = sbuf[(size_t)b * NU + t];
    __shared__ float sv[NU];
    __shared__ float fb[UU];
    sv[t] = s; __syncthreads();
    if (t < UU) {
        float m = 0.f;
        #pragma unroll
        for (int n = 0; n < NN; ++n) { float z = sv[n*16 + t]; m = fmaf(z, z, m); }
        fb[t] = sqrtf(m) / (1.f + m);   // == (m/(1+m)) / sqrt(m)
    }
    __syncthreads();
    vdst[(size_t)b * NU + t] = s * fb[t & 15];
}

// ---------------- heavy pass 2: db[j*10+n] += <u_hat, v> (atomic) --------
// grid (36 j-tiles of 32, 16 b-tiles of 16), block 320: jl = tid&31, n = tid>>5.
// W row processed in two u-halves: wf[64] live at a time -> no spills.
__global__ void __launch_bounds__(320, 2)
k_uhat_db(const float* __restrict__ xg, const float* __restrict__ wg,
          const float* __restrict__ v, float* __restrict__ db) {
    const int jt = blockIdx.x, bt = blockIdx.y;
    const int j0 = jt * 32, b0 = bt * 16;
    const int tid = threadIdx.x;
    const int jl = tid & 31;
    const int n  = tid >> 5;     // 0..9

    __shared__ float xs2[4096];  // [((i>>2)*16+b)*32 + jl]*4 + (i&3)
    __shared__ float vs2[16 * NU];

    for (int idx = tid; idx < 4096; idx += 320) {
        int jj = idx & 31;
        int r  = idx >> 5;
        int i  = r & 7;
        int b  = r >> 3;
        xs2[(((i >> 2)*16 + b)*32 + jj)*4 + (i & 3)] =
            xg[(size_t)(b0 + b) * (IU*JC) + i * JC + j0 + jj];
    }
    for (int idx = tid; idx < 16*NU; idx += 320)
        vs2[idx] = v[(size_t)b0 * NU + idx];
    __syncthreads();

    const int j = j0 + jl;
    const float* wrow = wg + (size_t)j * WROW + n * (UU*IU);

    float acc = 0.f;
    #pragma unroll
    for (int uh = 0; uh < 2; ++uh) {
        const float4* wp = reinterpret_cast<const float4*>(wrow + uh * 64);
        float wf[64];            // wf[u8*8 + i], u8 = u - uh*8
        #pragma unroll
        for (int r = 0; r < 16; ++r) {
            float4 wv = wp[r];
            wf[r*4+0] = wv.x; wf[r*4+1] = wv.y;
            wf[r*4+2] = wv.z; wf[r*4+3] = wv.w;
        }
        #pragma unroll 4
        for (int b = 0; b < 16; ++b) {
            const float4* xp0 = reinterpret_cast<const float4*>(&xs2[((b)*32 + jl)*4]);
            const float4* xp1 = reinterpret_cast<const float4*>(&xs2[((16 + b)*32 + jl)*4]);
            float4 xa = xp0[0], xb = xp1[0];
            const float4* vp = reinterpret_cast<const float4*>(&vs2[b*NU + n*16 + uh*8]);
            float4 v0 = vp[0], v1 = vp[1];
            float vr[8] = {v0.x,v0.y,v0.z,v0.w, v1.x,v1.y,v1.z,v1.w};
            #pragma unroll
            for (int u = 0; u < 8; ++u) {
                const float* w8 = &wf[u*8];
                float t;
                t = w8[0] * xa.x;
                t = fmaf(w8[1], xa.y, t); t = fmaf(w8[2], xa.z, t);
                t = fmaf(w8[3], xa.w, t); t = fmaf(w8[4], xb.x, t);
                t = fmaf(w8[5], xb.y, t); t = fmaf(w8[6], xb.z, t);
                t = fmaf(w8[7], xb.w, t);
                acc = fmaf(t, vr[u], acc);
            }
        }
    }
    atomicAdd(&db[(size_t)j * NN + n], acc);
}

// ---------------- b += db/B ----------------------------------------------
__global__ void k_update_b(const float* __restrict__ db, float* __restrict__ blog) {
    int k = blockIdx.x * 256 + threadIdx.x;
    if (k >= JN) return;
    blog[k] += db[k] * (1.f / (float)B);
}

extern "C" void kernel_launch(void* const* d_in, const int* in_sizes, int n_in,
                              void* d_out, int out_size, void* d_ws, size_t ws_size,
                              hipStream_t stream) {
    const float* x = (const float*)d_in[0];
    const float* w = (const float*)d_in[1];
    float* out = (float*)d_out;    // reference output dtype is float32

    float* ws   = (float*)d_ws;
    float* blog = ws;                 // 11520 floats
    float* c    = blog + JN;          // 11520
    float* sbuf = c + JN;             // 40960
    float* v    = sbuf + (size_t)B*NU;// 40960
    float* db   = v + (size_t)B*NU;   // 11520
    // total: 116480 floats = 465,920 bytes

    hipMemsetAsync(blog, 0, JN * sizeof(float), stream);

    for (int t = 0; t < 3; ++t) {
        k_softmax<<<NN, 256, 0, stream>>>(blog, c);
        hipMemsetAsync(sbuf, 0, (size_t)B * NU * sizeof(float), stream);
        k_uhat_s<<<dim3(18, 32), 320, 0, stream>>>(x, w, c, sbuf);
        // final iteration writes v directly to d_out (fp32)
        k_reduce_s<<<B, NU, 0, stream>>>(sbuf, (t == 2) ? out : v);
        if (t < 2) {
            hipMemsetAsync(db, 0, JN * sizeof(float), stream);
            k_uhat_db<<<dim3(36, 16), 320, 0, stream>>>(x, w, v, db);
            k_update_b<<<45, 256, 0, stream>>>(db, blog);
        }
    }
}